// Round 4
// baseline (4628.698 us; speedup 1.0000x reference)
//
#include <hip/hip_runtime.h>
#include <hip/hip_bf16.h>

#define NUM_B 2
#define NUM_H 16
#define SEQ   2048
#define EMB   1024
#define LOG2E 1.44269504088896340736f

// ---------- naive QKV GEMM: qkv[m,n] = x[m,:] . w_qkv[:,n] + b, scatter to Q/K/V [BH,S,D]
__global__ __launch_bounds__(256) void naive_qkv_kernel(
    const float* __restrict__ x, const float* __restrict__ w,
    const float* __restrict__ bias, float* __restrict__ Q,
    float* __restrict__ K, float* __restrict__ V) {
  int n = blockIdx.x * 256 + threadIdx.x;   // 0..3071  (grid.x = 12)
  int m = blockIdx.y;                        // 0..4095
  float acc = 0.f;
  const float* xr = x + (size_t)m * EMB;
  for (int k = 0; k < EMB; ++k)
    acc += xr[k] * w[(size_t)k * 3072 + n];
  acc += bias[n];
  int sec = n >> 10, h = (n >> 6) & (NUM_H - 1), d = n & 63;
  int b = m >> 11, s = m & (SEQ - 1);
  float* dst = (sec == 0) ? Q : (sec == 1) ? K : V;
  dst[(((size_t)(b * NUM_H + h)) * SEQ + s) * 64 + d] = acc;
}

// ---------- RoPE (GPT-NeoX rotate-half); Q gets 1/sqrt(D)=1/8 folded in
__global__ void rope_kernel(float* __restrict__ Q, float* __restrict__ K) {
  int idx = blockIdx.x * blockDim.x + threadIdx.x;  // over B*H*S*32
  int i = idx & 31;
  int bhs = idx >> 5;
  int s = bhs & (SEQ - 1);
  float inv = exp2f(-(float)i * (13.287712379549449f / 32.0f));  // 10000^(-i/32)
  float f = (float)s * inv;
  float sn, cs;
  sincosf(f, &sn, &cs);
  size_t base = (size_t)bhs * 64;
  float q1 = Q[base + i];
  float q2 = Q[base + i + 32];
  float k1 = K[base + i];
  float k2 = K[base + i + 32];
  Q[base + i]      = (q1 * cs - q2 * sn) * 0.125f;
  Q[base + i + 32] = (q2 * cs + q1 * sn) * 0.125f;
  K[base + i]      = k1 * cs - k2 * sn;
  K[base + i + 32] = k2 * cs + k1 * sn;
}

// ---------- naive causal attention: one 64-lane wave per (bh, q) row
__global__ __launch_bounds__(64) void naive_attn_kernel(
    const float* __restrict__ Q, const float* __restrict__ K,
    const float* __restrict__ V, float* __restrict__ O) {
  int bh = blockIdx.x & 31;
  int q = blockIdx.x >> 5;          // grid.x = 32*2048
  int lane = threadIdx.x;
  __shared__ float Qsh[64];
  __shared__ float psh[64];
  Qsh[lane] = Q[((size_t)bh * SEQ + q) * 64 + lane];
  __syncthreads();

  float mrun = -1e30f, lrun = 0.f, oacc = 0.f;
  for (int kv0 = 0; kv0 <= q; kv0 += 64) {
    int kv = kv0 + lane;
    float s = -1e30f;
    if (kv <= q) {
      s = 0.f;
      const float* Kr = K + ((size_t)bh * SEQ + kv) * 64;
      for (int d = 0; d < 64; ++d) s += Qsh[d] * Kr[d];
    }
    float mx = s;
    mx = fmaxf(mx, __shfl_xor(mx, 1, 64));
    mx = fmaxf(mx, __shfl_xor(mx, 2, 64));
    mx = fmaxf(mx, __shfl_xor(mx, 4, 64));
    mx = fmaxf(mx, __shfl_xor(mx, 8, 64));
    mx = fmaxf(mx, __shfl_xor(mx, 16, 64));
    mx = fmaxf(mx, __shfl_xor(mx, 32, 64));
    float mn = fmaxf(mrun, mx);
    float p = (kv <= q) ? exp2f((s - mn) * LOG2E) : 0.f;
    float ps = p;
    ps += __shfl_xor(ps, 1, 64);
    ps += __shfl_xor(ps, 2, 64);
    ps += __shfl_xor(ps, 4, 64);
    ps += __shfl_xor(ps, 8, 64);
    ps += __shfl_xor(ps, 16, 64);
    ps += __shfl_xor(ps, 32, 64);
    float al = exp2f((mrun - mn) * LOG2E);
    lrun = lrun * al + ps;
    oacc *= al;
    mrun = mn;
    __syncthreads();
    psh[lane] = p;
    __syncthreads();
    int lim = q - kv0 + 1;
    if (lim > 64) lim = 64;
    for (int kk = 0; kk < lim; ++kk)
      oacc += psh[kk] * V[((size_t)bh * SEQ + kv0 + kk) * 64 + lane];
  }
  int b = bh >> 4, h = bh & (NUM_H - 1);
  // O layout [B,S,H,D]
  O[(((size_t)b * SEQ + q) * NUM_H + h) * 64 + lane] = oacc / lrun;
}

// ---------- naive out-proj: out[m,n] = attn[m,:] . w_o[:,n] + b_o[n]
__global__ __launch_bounds__(256) void naive_oproj_kernel(
    const float* __restrict__ A, const float* __restrict__ w,
    const float* __restrict__ bias, float* __restrict__ out) {
  int n = blockIdx.x * 256 + threadIdx.x;   // 0..1023 (grid.x = 4)
  int m = blockIdx.y;                        // 0..4095
  float acc = 0.f;
  const float* ar = A + (size_t)m * EMB;
  for (int k = 0; k < EMB; ++k)
    acc += ar[k] * w[(size_t)k * EMB + n];
  acc += bias[n];
  out[(size_t)m * EMB + n] = acc;
}

extern "C" void kernel_launch(void* const* d_in, const int* in_sizes, int n_in,
                              void* d_out, int out_size, void* d_ws, size_t ws_size,
                              hipStream_t stream) {
  const float* x      = (const float*)d_in[0];
  const float* w_qkv  = (const float*)d_in[1];
  const float* b_qkv  = (const float*)d_in[2];
  const float* w_o    = (const float*)d_in[3];
  const float* b_o    = (const float*)d_in[4];
  float* out = (float*)d_out;

  float* ws   = (float*)d_ws;
  float* Qb   = ws;                      // [32,2048,64]  16MB
  float* Kb   = Qb + 4 * 1024 * 1024;    // [32,2048,64]  16MB
  float* Vb   = Kb + 4 * 1024 * 1024;    // [32,2048,64]  16MB
  float* attn = Vb + 4 * 1024 * 1024;    // [B,S,H,D]     16MB   (total 64MB)

  naive_qkv_kernel<<<dim3(12, 4096), 256, 0, stream>>>(x, w_qkv, b_qkv, Qb, Kb, Vb);
  rope_kernel<<<8192, 256, 0, stream>>>(Qb, Kb);
  naive_attn_kernel<<<32 * SEQ, 64, 0, stream>>>(Qb, Kb, Vb, attn);
  naive_oproj_kernel<<<dim3(4, 4096), 256, 0, stream>>>(attn, w_o, b_o, out);
}

// Round 5
// 291.391 us; speedup vs baseline: 15.8849x; 15.8849x over previous
//
#include <hip/hip_runtime.h>
#include <hip/hip_bf16.h>

typedef __hip_bfloat16 bf16_t;
typedef __attribute__((ext_vector_type(8))) __bf16 bf16x8;
typedef __attribute__((ext_vector_type(4))) float f32x4;
typedef __attribute__((ext_vector_type(4))) unsigned short ushort4v;

#define NUM_B 2
#define NUM_H 16
#define SEQ   2048
#define EMB   1024
#define LOG2E 1.44269504088896340736f

// ---------------- cast fp32 -> bf16, 4 elems/thread ----------------
__global__ void cast_f32_bf16_kernel(const float* __restrict__ src,
                                     bf16_t* __restrict__ dst) {
  int i = (blockIdx.x * 256 + threadIdx.x) * 4;
  f32x4 v = *(const f32x4*)&src[i];
  ushort4v p;
#pragma unroll
  for (int j = 0; j < 4; ++j)
    p[j] = __builtin_bit_cast(unsigned short, __float2bfloat16(v[j]));
  *(ushort4v*)&dst[i] = p;
}

// ---------------- cast+transpose: dst[C x R] (bf16) = src[R x C]^T (fp32) ----------------
__global__ void transpose_cast_kernel(const float* __restrict__ src,
                                      bf16_t* __restrict__ dst, int R, int C) {
  __shared__ float tile[32][33];
  int c0 = blockIdx.x * 32, r0 = blockIdx.y * 32;
  int tx = threadIdx.x & 31, ty = threadIdx.x >> 5;
#pragma unroll
  for (int i = 0; i < 4; ++i)
    tile[ty + i * 8][tx] = src[(size_t)(r0 + ty + i * 8) * C + c0 + tx];
  __syncthreads();
#pragma unroll
  for (int i = 0; i < 4; ++i)
    dst[(size_t)(c0 + ty + i * 8) * R + r0 + tx] = __float2bfloat16(tile[tx][ty + i * 8]);
}

// ---------------- GEMM: C = A[M,K]bf16 * Bt[N,K]bf16^T + bias(f32) ----------------
__device__ __forceinline__ void stage_tile(const bf16_t* __restrict__ G,
                                           int row0, int col0, int ld,
                                           bf16_t* Ls, int wave, int lane) {
  // 128x32 bf16 tile = 8192B = 512 chunks of 16B; LDS dest = wave-uniform
  // base (wave*1024 [+4096]) + lane*16 -- conforms to global_load_lds HW rule.
  int c0 = wave * 64 + lane;
  const char* g0 = (const char*)(G + (size_t)(row0 + (c0 >> 2)) * ld + col0) + (c0 & 3) * 16;
  char* l0 = (char*)Ls + c0 * 16;
  __builtin_amdgcn_global_load_lds((const __attribute__((address_space(1))) void*)g0,
                                   (__attribute__((address_space(3))) void*)l0, 16, 0, 0);
  int c1 = c0 + 256;
  const char* g1 = (const char*)(G + (size_t)(row0 + (c1 >> 2)) * ld + col0) + (c1 & 3) * 16;
  char* l1 = (char*)Ls + c1 * 16;
  __builtin_amdgcn_global_load_lds((const __attribute__((address_space(1))) void*)g1,
                                   (__attribute__((address_space(3))) void*)l1, 16, 0, 0);
}

// MODE 0: epilogue scatters bf16 into Q [BH,S,D], K [BH,S,D], Vt [BH,D,S]  (N=3072)
// MODE 1: plain fp32 store outf[m*Ndim + n]
template <int MODE>
__global__ __launch_bounds__(256) void gemm_bf16_kernel(
    const bf16_t* __restrict__ A, const bf16_t* __restrict__ Bt,
    const float* __restrict__ bias, bf16_t* __restrict__ out0,
    bf16_t* __restrict__ out1, bf16_t* __restrict__ out2,
    float* __restrict__ outf, int Ndim, int Kdim) {
  __shared__ __align__(16) bf16_t As[128 * 32];
  __shared__ __align__(16) bf16_t Bs[128 * 32];
  int tid = threadIdx.x;
  int wave = tid >> 6, lane = tid & 63;
  int lr = lane & 15, lq = lane >> 4;
  int m0 = blockIdx.x * 128, n0 = blockIdx.y * 128;
  int wm = (wave >> 1) * 64, wn = (wave & 1) * 64;
  f32x4 acc[4][4];
#pragma unroll
  for (int i = 0; i < 4; ++i)
#pragma unroll
    for (int j = 0; j < 4; ++j) acc[i][j] = (f32x4){0.f, 0.f, 0.f, 0.f};

  for (int k0 = 0; k0 < Kdim; k0 += 32) {
    __syncthreads();
    stage_tile(A, m0, k0, Kdim, As, wave, lane);
    stage_tile(Bt, n0, k0, Kdim, Bs, wave, lane);
    __syncthreads();
    bf16x8 af[4], bfr[4];
#pragma unroll
    for (int mt = 0; mt < 4; ++mt)
      af[mt] = *(const bf16x8*)&As[(wm + mt * 16 + lr) * 32 + lq * 8];
#pragma unroll
    for (int nt = 0; nt < 4; ++nt)
      bfr[nt] = *(const bf16x8*)&Bs[(wn + nt * 16 + lr) * 32 + lq * 8];
#pragma unroll
    for (int mt = 0; mt < 4; ++mt)
#pragma unroll
      for (int nt = 0; nt < 4; ++nt)
        acc[mt][nt] = __builtin_amdgcn_mfma_f32_16x16x32_bf16(af[mt], bfr[nt], acc[mt][nt], 0, 0, 0);
  }

#pragma unroll
  for (int nt = 0; nt < 4; ++nt) {
    int n = n0 + wn + nt * 16 + lr;
    float bv = bias[n];
    if (MODE == 0) {
      int sec = n >> 10;          // 0=q 1=k 2=v
      int h = (n >> 6) & (NUM_H - 1);
      int d = n & 63;
#pragma unroll
      for (int mt = 0; mt < 4; ++mt) {
        int mbase = m0 + wm + mt * 16 + lq * 4;   // 4 consecutive rows
        int b = mbase >> 11;
        int s = mbase & (SEQ - 1);
        int bh = b * NUM_H + h;
        if (sec == 2) {
          ushort4v pk;
#pragma unroll
          for (int r = 0; r < 4; ++r)
            pk[r] = __builtin_bit_cast(unsigned short, __float2bfloat16(acc[mt][nt][r] + bv));
          *(ushort4v*)&out2[((size_t)bh * 64 + d) * SEQ + s] = pk;
        } else {
          bf16_t* dst = (sec == 0) ? out0 : out1;
#pragma unroll
          for (int r = 0; r < 4; ++r)
            dst[((size_t)bh * SEQ + (s + r)) * 64 + d] = __float2bfloat16(acc[mt][nt][r] + bv);
        }
      }
    } else {
#pragma unroll
      for (int mt = 0; mt < 4; ++mt)
#pragma unroll
        for (int r = 0; r < 4; ++r) {
          int m = m0 + wm + mt * 16 + lq * 4 + r;
          outf[(size_t)m * Ndim + n] = acc[mt][nt][r] + bv;
        }
    }
  }
}

// ---------------- RoPE (GPT-NeoX rotate-half), Q gets 1/sqrt(D)=1/8 ----------------
__global__ void rope_kernel(bf16_t* __restrict__ Q, bf16_t* __restrict__ K) {
  int idx = blockIdx.x * blockDim.x + threadIdx.x;  // over B*H*S*32
  int i = idx & 31;
  int bhs = idx >> 5;
  int s = bhs & (SEQ - 1);
  float inv = exp2f(-(float)i * (13.287712379549449f / 32.0f));  // 10000^(-i/32)
  float f = (float)s * inv;
  float sn, cs;
  sincosf(f, &sn, &cs);
  size_t base = (size_t)bhs * 64;
  float q1 = __bfloat162float(Q[base + i]);
  float q2 = __bfloat162float(Q[base + i + 32]);
  float k1 = __bfloat162float(K[base + i]);
  float k2 = __bfloat162float(K[base + i + 32]);
  Q[base + i]      = __float2bfloat16((q1 * cs - q2 * sn) * 0.125f);
  Q[base + i + 32] = __float2bfloat16((q2 * cs + q1 * sn) * 0.125f);
  K[base + i]      = __float2bfloat16(k1 * cs - k2 * sn);
  K[base + i + 32] = __float2bfloat16(k2 * cs + k1 * sn);
}

// ---------------- flash attention: 1 wave = 16 query rows, kv chunks of 32 ----------------
__global__ __launch_bounds__(64) void flash_attn_kernel(
    const bf16_t* __restrict__ Q, const bf16_t* __restrict__ K,
    const bf16_t* __restrict__ Vt, bf16_t* __restrict__ O) {
  __shared__ __align__(16) bf16_t Psh[16 * 32];
  int lane = threadIdx.x;
  int lr = lane & 15, lq = lane >> 4;
  int tile = blockIdx.x >> 5;     // 0..127
  int bh = blockIdx.x & 31;
  int q0 = tile * 16;
  const bf16_t* Qb = Q + (size_t)bh * SEQ * 64;
  const bf16_t* Kb = K + (size_t)bh * SEQ * 64;
  const bf16_t* Vb = Vt + (size_t)bh * 64 * SEQ;

  bf16x8 aq0 = *(const bf16x8*)&Qb[(size_t)(q0 + lr) * 64 + lq * 8];
  bf16x8 aq1 = *(const bf16x8*)&Qb[(size_t)(q0 + lr) * 64 + 32 + lq * 8];

  f32x4 Oacc[4];
#pragma unroll
  for (int dt = 0; dt < 4; ++dt) Oacc[dt] = (f32x4){0.f, 0.f, 0.f, 0.f};
  float mrow[4] = {-1e30f, -1e30f, -1e30f, -1e30f};
  float lrow[4] = {0.f, 0.f, 0.f, 0.f};

  int nchunk = (q0 + 16 + 31) >> 5;
  for (int ch = 0; ch < nchunk; ++ch) {
    int kv0 = ch * 32;
    bf16x8 kb00 = *(const bf16x8*)&Kb[(size_t)(kv0 + lr) * 64 + lq * 8];
    bf16x8 kb01 = *(const bf16x8*)&Kb[(size_t)(kv0 + lr) * 64 + 32 + lq * 8];
    bf16x8 kb10 = *(const bf16x8*)&Kb[(size_t)(kv0 + 16 + lr) * 64 + lq * 8];
    bf16x8 kb11 = *(const bf16x8*)&Kb[(size_t)(kv0 + 16 + lr) * 64 + 32 + lq * 8];
    f32x4 s0 = (f32x4){0.f, 0.f, 0.f, 0.f}, s1 = (f32x4){0.f, 0.f, 0.f, 0.f};
    s0 = __builtin_amdgcn_mfma_f32_16x16x32_bf16(aq0, kb00, s0, 0, 0, 0);
    s0 = __builtin_amdgcn_mfma_f32_16x16x32_bf16(aq1, kb01, s0, 0, 0, 0);
    s1 = __builtin_amdgcn_mfma_f32_16x16x32_bf16(aq0, kb10, s1, 0, 0, 0);
    s1 = __builtin_amdgcn_mfma_f32_16x16x32_bf16(aq1, kb11, s1, 0, 0, 0);

    if (kv0 + 31 > q0) {  // diagonal chunk: causal mask
#pragma unroll
      for (int r = 0; r < 4; ++r) {
        int q = q0 + lq * 4 + r;
        if (kv0 + lr > q) s0[r] = -1e30f;
        if (kv0 + 16 + lr > q) s1[r] = -1e30f;
      }
    }

    float p0v[4], p1v[4], al[4];
#pragma unroll
    for (int r = 0; r < 4; ++r) {
      float mx = fmaxf(s0[r], s1[r]);
      mx = fmaxf(mx, __shfl_xor(mx, 1, 64));
      mx = fmaxf(mx, __shfl_xor(mx, 2, 64));
      mx = fmaxf(mx, __shfl_xor(mx, 4, 64));
      mx = fmaxf(mx, __shfl_xor(mx, 8, 64));
      float mn = fmaxf(mrow[r], mx);
      float p0 = exp2f((s0[r] - mn) * LOG2E);
      float p1 = exp2f((s1[r] - mn) * LOG2E);
      float ps = p0 + p1;
      ps += __shfl_xor(ps, 1, 64);
      ps += __shfl_xor(ps, 2, 64);
      ps += __shfl_xor(ps, 4, 64);
      ps += __shfl_xor(ps, 8, 64);
      al[r] = exp2f((mrow[r] - mn) * LOG2E);
      lrow[r] = lrow[r] * al[r] + ps;
      mrow[r] = mn;
      p0v[r] = p0;
      p1v[r] = p1;
    }
#pragma unroll
    for (int dt = 0; dt < 4; ++dt)
#pragma unroll
      for (int r = 0; r < 4; ++r) Oacc[dt][r] *= al[r];

    // P (C-layout) -> A-layout via LDS
    __syncthreads();
#pragma unroll
    for (int r = 0; r < 4; ++r) {
      Psh[(lq * 4 + r) * 32 + lr] = __float2bfloat16(p0v[r]);
      Psh[(lq * 4 + r) * 32 + 16 + lr] = __float2bfloat16(p1v[r]);
    }
    __syncthreads();
    bf16x8 ap = *(const bf16x8*)&Psh[lr * 32 + lq * 8];
#pragma unroll
    for (int dt = 0; dt < 4; ++dt) {
      bf16x8 vb = *(const bf16x8*)&Vb[(size_t)(dt * 16 + lr) * SEQ + kv0 + lq * 8];
      Oacc[dt] = __builtin_amdgcn_mfma_f32_16x16x32_bf16(ap, vb, Oacc[dt], 0, 0, 0);
    }
  }

  int b = bh >> 4, h = bh & (NUM_H - 1);
#pragma unroll
  for (int dt = 0; dt < 4; ++dt)
#pragma unroll
    for (int r = 0; r < 4; ++r) {
      int q = q0 + lq * 4 + r;
      O[(((size_t)b * SEQ + q) * NUM_H + h) * 64 + dt * 16 + lr] =
          __float2bfloat16(Oacc[dt][r] / lrow[r]);
    }
}

extern "C" void kernel_launch(void* const* d_in, const int* in_sizes, int n_in,
                              void* d_out, int out_size, void* d_ws, size_t ws_size,
                              hipStream_t stream) {
  const float* x      = (const float*)d_in[0];
  const float* w_qkv  = (const float*)d_in[1];
  const float* b_qkv  = (const float*)d_in[2];
  const float* w_o    = (const float*)d_in[3];
  const float* b_o    = (const float*)d_in[4];
  float* out = (float*)d_out;

  bf16_t* ws    = (bf16_t*)d_ws;
  bf16_t* xb    = ws;                       // [4096,1024]   8MB
  bf16_t* wqkvT = xb + 4 * 1024 * 1024;     // [3072,1024]   6MB
  bf16_t* woT   = wqkvT + 3072 * 1024;      // [1024,1024]   2MB
  bf16_t* Qb    = woT + 1024 * 1024;        // [32,2048,64]  8MB
  bf16_t* Kb    = Qb + 4 * 1024 * 1024;     // [32,2048,64]  8MB
  bf16_t* Vt    = Kb + 4 * 1024 * 1024;     // [32,64,2048]  8MB
  bf16_t* attn  = Vt + 4 * 1024 * 1024;     // [4096,1024]   8MB  (48MB total)

  cast_f32_bf16_kernel<<<4096, 256, 0, stream>>>(x, xb);
  transpose_cast_kernel<<<dim3(96, 32), 256, 0, stream>>>(w_qkv, wqkvT, 1024, 3072);
  transpose_cast_kernel<<<dim3(32, 32), 256, 0, stream>>>(w_o, woT, 1024, 1024);
  gemm_bf16_kernel<0><<<dim3(32, 24), 256, 0, stream>>>(xb, wqkvT, b_qkv, Qb, Kb, Vt, nullptr, 3072, 1024);
  rope_kernel<<<8192, 256, 0, stream>>>(Qb, Kb);
  flash_attn_kernel<<<4096, 64, 0, stream>>>(Qb, Kb, Vt, attn);
  gemm_bf16_kernel<1><<<dim3(32, 8), 256, 0, stream>>>(attn, woT, b_o, nullptr, nullptr, nullptr, out, 1024, 1024);
}